// Round 8
// baseline (94.494 us; speedup 1.0000x reference)
//
#include <hip/hip_runtime.h>

typedef float  f32x4  __attribute__((ext_vector_type(4)));
typedef short  short8 __attribute__((ext_vector_type(8)));
typedef __bf16 bf16x8 __attribute__((ext_vector_type(8)));

#define DEV static __device__ __forceinline__
#define SB  __builtin_amdgcn_sched_barrier(0)

DEV f32x4 mfma16(short8 a, short8 b, f32x4 c) {
  return __builtin_amdgcn_mfma_f32_16x16x32_bf16(
      __builtin_bit_cast(bf16x8, a), __builtin_bit_cast(bf16x8, b), c, 0, 0, 0);
}

// split f32 into bf16 hi (truncated) + bf16 lo (RNE of residual)
DEV void splitf(float f, unsigned short& hi, unsigned short& lo) {
  unsigned u = __builtin_bit_cast(unsigned, f);
  hi = (unsigned short)(u >> 16);
  float hf = __builtin_bit_cast(float, u & 0xFFFF0000u);
  float r = f - hf;
  unsigned v = __builtin_bit_cast(unsigned, r);
  lo = (unsigned short)((v + 0x7FFFu + ((v >> 16) & 1u)) >> 16);
}

// async global->LDS, 16B per lane, wave-uniform LDS base
DEV void gload16(const unsigned short* g, unsigned short* lds) {
  __builtin_amdgcn_global_load_lds(
      (const __attribute__((address_space(1))) void*)g,
      (__attribute__((address_space(3))) void*)lds, 16, 0, 0);
}

#define DDIM 640
#define KCH  20                    // 640 / 32 k-chunks for GEMM1
#define MKP_ELEMS (KCH*2*4*64*8)   // 81920 ushorts = 160KB
#define MVP_OFF   MKP_ELEMS

// Pack Mk / Mv^T in MFMA fragment order as bf16 hi/lo (see R1 comments).
__global__ void ea_pack(const float* __restrict__ Mk, const float* __restrict__ Mv,
                        unsigned short* __restrict__ ws) {
  int tid = blockIdx.x * 256 + threadIdx.x;
  unsigned short* MkP = ws;
  unsigned short* MvP = ws + MVP_OFF;
  if (tid < 5120) {
    int c = tid >> 8;
    int g = (tid >> 6) & 3;
    int l = tid & 63;
    int t = l & 15, q = l >> 4;
    const float* src = Mk + (16*g + t) * DDIM + 32*c + 8*q;
    unsigned short* dh = MkP + (((c*2 + 0)*4 + g)*64 + l)*8;
    unsigned short* dl = MkP + (((c*2 + 1)*4 + g)*64 + l)*8;
#pragma unroll
    for (int j = 0; j < 8; ++j) splitf(src[j], dh[j], dl[j]);
  } else if (tid < 10240) {
    int s = tid - 5120;
    int n = s >> 7;
    int c = (s >> 6) & 1;
    int l = s & 63;
    int t = l & 15, q = l >> 4;
    const float* src = Mv + (32*c + 8*q) * DDIM + 16*n + t;
    unsigned short* dh = MvP + (((n*2 + c)*2 + 0)*64 + l)*8;
    unsigned short* dl = MvP + (((n*2 + c)*2 + 1)*64 + l)*8;
#pragma unroll
    for (int j = 0; j < 8; ++j) splitf(src[j*DDIM], dh[j], dl[j]);
  }
}

#define LOADX(X0, X1, c) { X0 = *(const f32x4*)(xp + 32*(c)); \
                           X1 = *(const f32x4*)(xp + 32*(c) + 4); }

#define SPLITX(X0, X1)                                                       \
  splitf(X0[0], ah.u[0], al.u[0]); splitf(X0[1], ah.u[1], al.u[1]);          \
  splitf(X0[2], ah.u[2], al.u[2]); splitf(X0[3], ah.u[3], al.u[3]);          \
  splitf(X1[0], ah.u[4], al.u[4]); splitf(X1[1], ah.u[5], al.u[5]);          \
  splitf(X1[2], ah.u[6], al.u[6]); splitf(X1[3], ah.u[7], al.u[7]);

#define MFMAS()                                                              \
  acc[0] = mfma16(ah.s, fh0, acc[0]); acc[1] = mfma16(ah.s, fh1, acc[1]);    \
  acc[2] = mfma16(ah.s, fh2, acc[2]); acc[3] = mfma16(ah.s, fh3, acc[3]);    \
  acc[0] = mfma16(al.s, fh0, acc[0]); acc[1] = mfma16(al.s, fh1, acc[1]);    \
  acc[2] = mfma16(al.s, fh2, acc[2]); acc[3] = mfma16(al.s, fh3, acc[3]);    \
  acc[0] = mfma16(ah.s, fl0, acc[0]); acc[1] = mfma16(ah.s, fl1, acc[1]);    \
  acc[2] = mfma16(ah.s, fl2, acc[2]); acc[3] = mfma16(ah.s, fl3, acc[3]);

// One G1 K-step: stage chunk c+1; ds_read + CONSUME chunk c's x (SPLITX);
// THEN reload the freed named regs with chunk c+4 (R6's consume-then-reload
// order — R7's bug was reload-before-consume); 12 MFMA; counted vmcnt(2)
// (stage-gloads drained, the 2 newest x-loads stay in flight) + raw barrier.
#define G1_ITER(c, XA, XB) {                                                 \
  SB;                                                                        \
  if ((c) + 1 < KCH) {                                                       \
    const unsigned short* gs = MkP + ((c)+1)*4096 + sgl;                     \
    unsigned short* ld = &Stg[((c)+1) & 1][sgw];                             \
    gload16(gs, ld); gload16(gs + 512, ld + 512);                            \
  }                                                                          \
  SB;                                                                        \
  { const unsigned short* s_ = &Stg[(c) & 1][l*8];                           \
    fh0 = *(const short8*)(s_);        fh1 = *(const short8*)(s_ + 512);     \
    fh2 = *(const short8*)(s_ + 1024); fh3 = *(const short8*)(s_ + 1536);    \
    fl0 = *(const short8*)(s_ + 2048); fl1 = *(const short8*)(s_ + 2560);    \
    fl2 = *(const short8*)(s_ + 3072); fl3 = *(const short8*)(s_ + 3584);    \
    SPLITX(XA, XB)                                                           \
    SB;                                                                      \
    if ((c) + 4 < KCH) { LOADX(XA, XB, (c)+4) }                              \
    SB;                                                                      \
    MFMAS() }                                                                \
  SB;                                                                        \
  asm volatile("s_waitcnt vmcnt(2)" ::: "memory");                           \
  SB;                                                                        \
  __builtin_amdgcn_s_barrier();                                              \
  SB;                                                                        \
}

// One G2 phase: stage n-pair P+1 into Stg[B^1], compute n=2P,2P+1 from
// Stg[B]; vmcnt(8) leaves this phase's 8 stores outstanding, stage complete.
#define G2_PHASE(P, B) {                                                     \
  SB;                                                                        \
  if ((P) + 1 < 20) {                                                        \
    const unsigned short* gs = MvP + ((P)+1)*4096 + sgl;                     \
    unsigned short* ld = &Stg[(B) ^ 1][sgw];                                 \
    gload16(gs, ld); gload16(gs + 512, ld + 512);                            \
  }                                                                          \
  SB;                                                                        \
  { const unsigned short* s_ = &Stg[B][l*8];                                 \
    short8 vh0 = *(const short8*)(s_);        short8 vl0 = *(const short8*)(s_ + 512);  \
    short8 vh1 = *(const short8*)(s_ + 1024); short8 vl1 = *(const short8*)(s_ + 1536); \
    short8 wh0 = *(const short8*)(s_ + 2048); short8 wl0 = *(const short8*)(s_ + 2560); \
    short8 wh1 = *(const short8*)(s_ + 3072); short8 wl1 = *(const short8*)(s_ + 3584); \
    f32x4 o0 = (f32x4){0.f,0.f,0.f,0.f};                                     \
    o0 = mfma16(aH0, vh0, o0); o0 = mfma16(aL0, vh0, o0);                    \
    o0 = mfma16(aH0, vl0, o0); o0 = mfma16(aH1, vh1, o0);                    \
    o0 = mfma16(aL1, vh1, o0); o0 = mfma16(aH1, vl1, o0);                    \
    f32x4 o1 = (f32x4){0.f,0.f,0.f,0.f};                                     \
    o1 = mfma16(aH0, wh0, o1); o1 = mfma16(aL0, wh0, o1);                    \
    o1 = mfma16(aH0, wl0, o1); o1 = mfma16(aH1, wh1, o1);                    \
    o1 = mfma16(aL1, wh1, o1); o1 = mfma16(aH1, wl1, o1);                    \
    float* p0 = opb + 32*(P);                                                \
    float* p1 = p0 + 16;                                                     \
    p0[0] = o0[0]; p0[DDIM] = o0[1]; p0[2*DDIM] = o0[2]; p0[3*DDIM] = o0[3]; \
    p1[0] = o1[0]; p1[DDIM] = o1[1]; p1[2*DDIM] = o1[2]; p1[3*DDIM] = o1[3]; \
  }                                                                          \
  SB;                                                                        \
  asm volatile("s_waitcnt vmcnt(8)" ::: "memory");                           \
  SB;                                                                        \
  __builtin_amdgcn_s_barrier();                                              \
  SB;                                                                        \
}

// 4-wave blocks, 64 rows/block (16/wave), grid 1024 = 4 blocks/CU.
// Fragments staged once per block via global_load_lds (dbuf LDS), shared by
// all 4 waves; x streamed per-wave via named-register distance-4 prefetch.
__global__ __launch_bounds__(256, 4) void ea_main(const float* __restrict__ x,
                                                  const unsigned short* __restrict__ MkP,
                                                  const unsigned short* __restrict__ MvP,
                                                  float* __restrict__ out) {
  __shared__ __align__(16) unsigned short Stg[2][4096];     // 16KB frag dbuf (G1 chunk / G2 n-pair)
  __shared__ __align__(16) unsigned short Wh[4][16][64];    // 8KB
  __shared__ __align__(16) unsigned short Wl[4][16][64];    // 8KB
  const int tid = threadIdx.x;
  const int w = tid >> 6;
  const int l = tid & 63;
  const int t = l & 15;
  const int q = l >> 4;
  const int sgl = w*1024 + l*8;     // per-lane src offset (ushorts)
  const int sgw = w*1024;           // wave-uniform LDS base (ushorts)
  const long row0 = (long)blockIdx.x * 64 + 16*w;

  // ---------------- GEMM1 ----------------
  const float* xp = x + (row0 + t) * DDIM + 8*q;
  f32x4 acc[4];
#pragma unroll
  for (int g = 0; g < 4; ++g) acc[g] = (f32x4){0.f, 0.f, 0.f, 0.f};

  f32x4 x00,x01,x10,x11,x20,x21,x30,x31;
  short8 fh0,fh1,fh2,fh3, fl0,fl1,fl2,fl3;
  union { short8 s; unsigned short u[8]; } ah, al;

  // prologue: stage chunk 0, then 8 x loads; vmcnt(8) leaves x in flight
  SB;
  gload16(MkP + sgl, &Stg[0][sgw]); gload16(MkP + sgl + 512, &Stg[0][sgw + 512]);
  SB;
  LOADX(x00,x01, 0) LOADX(x10,x11, 1) LOADX(x20,x21, 2) LOADX(x30,x31, 3)
  SB;
  asm volatile("s_waitcnt vmcnt(8)" ::: "memory");
  SB;
  __builtin_amdgcn_s_barrier();
  SB;

  G1_ITER( 0,x00,x01) G1_ITER( 1,x10,x11) G1_ITER( 2,x20,x21) G1_ITER( 3,x30,x31)
  G1_ITER( 4,x00,x01) G1_ITER( 5,x10,x11) G1_ITER( 6,x20,x21) G1_ITER( 7,x30,x31)
  G1_ITER( 8,x00,x01) G1_ITER( 9,x10,x11) G1_ITER(10,x20,x21) G1_ITER(11,x30,x31)
  G1_ITER(12,x00,x01) G1_ITER(13,x10,x11) G1_ITER(14,x20,x21) G1_ITER(15,x30,x31)
  G1_ITER(16,x00,x01) G1_ITER(17,x10,x11) G1_ITER(18,x20,x21) G1_ITER(19,x30,x31)

  // G2 prologue stage (pair 0) issued early; latency hides under softmax
  SB;
  gload16(MvP + sgl, &Stg[0][sgw]); gload16(MvP + sgl + 512, &Stg[0][sgw + 512]);
  SB;

  // ---------------- softmax (in-register, per wave) ----------------
  float rmax[4], rsum[4];
#pragma unroll
  for (int j = 0; j < 4; ++j)
    rmax[j] = fmaxf(fmaxf(acc[0][j], acc[1][j]), fmaxf(acc[2][j], acc[3][j]));
#pragma unroll
  for (int mk = 1; mk <= 8; mk <<= 1) {
#pragma unroll
    for (int j = 0; j < 4; ++j)
      rmax[j] = fmaxf(rmax[j], __shfl_xor(rmax[j], mk, 64));
  }
#pragma unroll
  for (int g = 0; g < 4; ++g)
#pragma unroll
    for (int j = 0; j < 4; ++j)
      acc[g][j] = exp2f((acc[g][j] - rmax[j]) * 1.44269504f);
#pragma unroll
  for (int j = 0; j < 4; ++j)
    rsum[j] = (acc[0][j] + acc[1][j]) + (acc[2][j] + acc[3][j]);
#pragma unroll
  for (int mk = 1; mk <= 8; mk <<= 1) {
#pragma unroll
    for (int j = 0; j < 4; ++j)
      rsum[j] += __shfl_xor(rsum[j], mk, 64);
  }
#pragma unroll
  for (int j = 0; j < 4; ++j) rsum[j] = 1.0f / rsum[j];

  // W -> private LDS slab, XOR swizzle (0-conflict)
#pragma unroll
  for (int g = 0; g < 4; ++g)
#pragma unroll
    for (int j = 0; j < 4; ++j) {
      float wt = acc[g][j] * rsum[j];
      unsigned short hi, lo;
      splitf(wt, hi, lo);
      int row = 4*q + j;
      int ms  = (16*g + t) ^ ((row & 7) << 3);
      Wh[w][row][ms] = hi;
      Wl[w][row][ms] = lo;
    }
  asm volatile("s_waitcnt lgkmcnt(0)" ::: "memory");
  SB;

  // hoisted GEMM2 A-fragments (wave-private)
  short8 aH0, aH1, aL0, aL1;
  {
    const int sw  = (t & 7) << 3;
    const int ms0 = (8*q) ^ sw;
    const int ms1 = (32 + 8*q) ^ sw;
    aH0 = *(const short8*)&Wh[w][t][ms0];
    aH1 = *(const short8*)&Wh[w][t][ms1];
    aL0 = *(const short8*)&Wl[w][t][ms0];
    aL1 = *(const short8*)&Wl[w][t][ms1];
  }
  SB;
  asm volatile("s_waitcnt vmcnt(0)" ::: "memory");   // pair 0 staged
  SB;
  __builtin_amdgcn_s_barrier();
  SB;

  // ---------------- GEMM2: 20 n-pair phases ----------------
  float* opb = out + (row0 + 4*q) * DDIM + t;
#pragma unroll 1
  for (int pp = 0; pp < 20; pp += 2) {
    G2_PHASE(pp,     0)
    G2_PHASE(pp + 1, 1)
  }
}

extern "C" void kernel_launch(void* const* d_in, const int* in_sizes, int n_in,
                              void* d_out, int out_size, void* d_ws, size_t ws_size,
                              hipStream_t stream) {
  const float* x  = (const float*)d_in[0];
  const float* Mk = (const float*)d_in[1];
  const float* Mv = (const float*)d_in[2];
  float* outp = (float*)d_out;
  unsigned short* ws = (unsigned short*)d_ws;

  ea_pack<<<40, 256, 0, stream>>>(Mk, Mv, ws);
  ea_main<<<1024, 256, 0, stream>>>(x, ws, ws + MVP_OFF, outp);
}